// Round 1
// baseline (646.089 us; speedup 1.0000x reference)
//
#include <hip/hip_runtime.h>

#define DBITS 18

__device__ __forceinline__ int swzi(int j){ return j ^ ((j >> 4) & 15); }

__device__ __forceinline__ unsigned pack_bf2(float r, float i){
  unsigned ur = __float_as_uint(r), ui = __float_as_uint(i);
  ur = (ur + 0x7FFFu + ((ur >> 16) & 1u)) >> 16;
  ui = (ui + 0x7FFFu + ((ui >> 16) & 1u)) & 0xFFFF0000u;
  return ur | ui;
}
__device__ __forceinline__ float2 unpack_bf2(unsigned u){
  return make_float2(__uint_as_float(u << 16), __uint_as_float(u & 0xFFFF0000u));
}

// apply 2x2 complex gate on the c-index bit with stride S (S = 1<<bit)
template<int S>
__device__ __forceinline__ void apply_gate(float ar[16], float ai[16], const float* __restrict__ g){
  const float u0r=g[0],u0i=g[1],u1r=g[2],u1i=g[3],u2r=g[4],u2i=g[5],u3r=g[6],u3i=g[7];
  #pragma unroll
  for (int h = 0; h < 8; ++h){
    const int c0 = ((h & ~(S-1)) << 1) | (h & (S-1));
    const int c1 = c0 | S;
    const float a0r=ar[c0], a0i=ai[c0], a1r=ar[c1], a1i=ai[c1];
    ar[c0] = u0r*a0r - u0i*a0i + u1r*a1r - u1i*a1i;
    ai[c0] = u0r*a0i + u0i*a0r + u1r*a1i + u1i*a1r;
    ar[c1] = u2r*a0r - u2i*a0i + u3r*a1r - u3i*a1i;
    ai[c1] = u2r*a0i + u2i*a0r + u3r*a1i + u3i*a1r;
  }
}

// deposit t's 10 bits into the complement of group-mask GM (14-bit local space)
template<int GM>
__device__ __forceinline__ int jbase_of(int t){
  int j = 0, src = 0;
  #pragma unroll
  for (int p = 0; p < 14; ++p){
    if (!((GM >> p) & 1)){ j |= ((t >> src) & 1) << p; ++src; }
  }
  return j;
}
template<int P0,int P1x,int P2x,int P3x>
__device__ __forceinline__ int cdep(int c){
  return ((c&1)<<P0) | (((c>>1)&1)<<P1x) | (((c>>2)&1)<<P2x) | (((c>>3)&1)<<P3x);
}
__host__ __device__ constexpr int wire_of(int p, int SL, int SH){
  return 17 - (p < SL ? p : p - SL + SH);
}

// middle round: LDS -> regs -> (optional CZ sign) -> gates -> LDS
template<int GM,int P0,int P1x,int P2x,int P3x,int NG,int LYR,int SL,int SH,bool SIGN>
__device__ __forceinline__ void round_mid(float2* lds, int t, int f, const float* __restrict__ gates){
  const int jb = jbase_of<GM>(t);
  float ar[16], ai[16];
  #pragma unroll
  for (int c = 0; c < 16; ++c){
    const int j = jb | cdep<P0,P1x,P2x,P3x>(c);
    float2 v = lds[swzi(j)];
    if (SIGN){
      const int gg = ((j >> SL) << SH) | (f << SL) | (j & ((1 << SL) - 1));
      const unsigned sb = (unsigned)(__popc(gg & (gg >> 1)) & 1) << 31;
      v.x = __uint_as_float(__float_as_uint(v.x) ^ sb);
      v.y = __uint_as_float(__float_as_uint(v.y) ^ sb);
    }
    ar[c] = v.x; ai[c] = v.y;
  }
  if (NG >= 1) apply_gate<1>(ar, ai, gates + (LYR*18 + wire_of(P0,SL,SH))*8);
  if (NG >= 2) apply_gate<2>(ar, ai, gates + (LYR*18 + wire_of(P1x,SL,SH))*8);
  if (NG >= 3) apply_gate<4>(ar, ai, gates + (LYR*18 + wire_of(P2x,SL,SH))*8);
  if (NG >= 4) apply_gate<8>(ar, ai, gates + (LYR*18 + wire_of(P3x,SL,SH))*8);
  #pragma unroll
  for (int c = 0; c < 16; ++c){
    const int j = jb | cdep<P0,P1x,P2x,P3x>(c);
    lds[swzi(j)] = make_float2(ar[c], ai[c]);
  }
}

// final round of passes 1..3: LDS -> regs -> gates -> pack bf16 -> global
template<int GM,int P0,int P1x,int P2x,int P3x,int NG,int LYR,int SL,int SH>
__device__ __forceinline__ void round_out(const float2* lds, int t, int f, unsigned stBase,
                                          unsigned* __restrict__ st, const float* __restrict__ gates){
  const int jb = jbase_of<GM>(t);
  float ar[16], ai[16];
  #pragma unroll
  for (int c = 0; c < 16; ++c){
    const int j = jb | cdep<P0,P1x,P2x,P3x>(c);
    float2 v = lds[swzi(j)];
    ar[c] = v.x; ai[c] = v.y;
  }
  if (NG >= 1) apply_gate<1>(ar, ai, gates + (LYR*18 + wire_of(P0,SL,SH))*8);
  if (NG >= 2) apply_gate<2>(ar, ai, gates + (LYR*18 + wire_of(P1x,SL,SH))*8);
  if (NG >= 3) apply_gate<4>(ar, ai, gates + (LYR*18 + wire_of(P2x,SL,SH))*8);
  if (NG >= 4) apply_gate<8>(ar, ai, gates + (LYR*18 + wire_of(P3x,SL,SH))*8);
  #pragma unroll
  for (int c = 0; c < 16; ++c){
    const int j = jb | cdep<P0,P1x,P2x,P3x>(c);
    const int gg = ((j >> SL) << SH) | (f << SL) | (j & ((1 << SL) - 1));
    st[stBase + gg] = pack_bf2(ar[c], ai[c]);
  }
}

// pass-4 last round: LDS -> regs -> gates -> weighted-prob partial sum
template<int GM,int P0,int P1x,int P2x,int P3x,int SL,int SH>
__device__ __forceinline__ float round_reduce(const float2* lds, int t, int f,
                                              const float* __restrict__ gates,
                                              const float* __restrict__ head_w){
  const int jb = jbase_of<GM>(t);
  float ar[16], ai[16];
  #pragma unroll
  for (int c = 0; c < 16; ++c){
    const int j = jb | cdep<P0,P1x,P2x,P3x>(c);
    float2 v = lds[swzi(j)];
    ar[c] = v.x; ai[c] = v.y;
  }
  apply_gate<1>(ar, ai, gates + (2*18 + wire_of(P0,SL,SH))*8);
  apply_gate<2>(ar, ai, gates + (2*18 + wire_of(P1x,SL,SH))*8);
  apply_gate<4>(ar, ai, gates + (2*18 + wire_of(P2x,SL,SH))*8);
  apply_gate<8>(ar, ai, gates + (2*18 + wire_of(P3x,SL,SH))*8);

  const int g0 = ((jb >> SL) << SH) | (f << SL) | (jb & ((1 << SL) - 1));
  float cb = 0.f;
  #pragma unroll
  for (int k = 0; k < 18; ++k){
    const float hw = head_w[17 - k];
    cb += ((g0 >> k) & 1) ? -hw : hw;
  }
  const float d0 = -2.f * head_w[17 - (P0 - SL + SH)];
  const float d1 = -2.f * head_w[17 - (P1x - SL + SH)];
  const float d2 = -2.f * head_w[17 - (P2x - SL + SH)];
  const float d3 = -2.f * head_w[17 - (P3x - SL + SH)];
  float acc = 0.f;
  #pragma unroll
  for (int c = 0; c < 16; ++c){
    float coef = cb;
    if (c & 1) coef += d0;
    if (c & 2) coef += d1;
    if (c & 4) coef += d2;
    if (c & 8) coef += d3;
    acc += coef * (ar[c]*ar[c] + ai[c]*ai[c]);
  }
  return acc;
}

template<int PASS>
__global__ __launch_bounds__(1024)
void qpass(const float* __restrict__ sr, const float* __restrict__ si,
           unsigned* __restrict__ st, const float* __restrict__ gates,
           const float* __restrict__ head_w, float* __restrict__ partials,
           int batch0)
{
  constexpr int SL = (PASS==1)?14:(PASS==2)?10:(PASS==3)?6:2;
  constexpr int SH = (PASS==1)?14:(PASS==2)?14:(PASS==3)?10:6;
  __shared__ float2 lds[16384];
  const int t = threadIdx.x;

  // XCD-aware bijective swizzle: consecutive logical ids share an XCD (L2 reuse)
  const int nwg = (int)gridDim.x;
  const int p = (int)blockIdx.x;
  const int q = nwg >> 3, r = nwg & 7, x = p & 7, m = p >> 3;
  const int logical = (x < r ? x*(q+1) : r*(q+1) + (x-r)*q) + m;
  const int f  = logical & 15;
  const int bl = logical >> 4;
  const int bg = batch0 + bl;
  const unsigned stBase = ((unsigned)bl) << DBITS;
  const size_t  inBase  = ((size_t)bg) << DBITS;

  // ---- Round 1: global -> regs, gates on local bits 10..13, -> LDS ----
  {
    constexpr int LYR = (PASS==1)?0:(PASS==2)?0:(PASS==3)?1:2;
    float ar[16], ai[16];
    #pragma unroll
    for (int c = 0; c < 16; ++c){
      const int j = t | (c << 10);
      const int gg = ((j >> SL) << SH) | (f << SL) | (j & ((1 << SL) - 1));
      if (PASS == 1){
        ar[c] = sr[inBase + (size_t)gg];
        ai[c] = si[inBase + (size_t)gg];
      } else {
        float2 v = unpack_bf2(st[stBase + (unsigned)gg]);
        ar[c] = v.x; ai[c] = v.y;
      }
    }
    apply_gate<1>(ar, ai, gates + (LYR*18 + wire_of(10,SL,SH))*8);
    apply_gate<2>(ar, ai, gates + (LYR*18 + wire_of(11,SL,SH))*8);
    apply_gate<4>(ar, ai, gates + (LYR*18 + wire_of(12,SL,SH))*8);
    apply_gate<8>(ar, ai, gates + (LYR*18 + wire_of(13,SL,SH))*8);
    #pragma unroll
    for (int c = 0; c < 16; ++c){
      const int j = t | (c << 10);
      lds[swzi(j)] = make_float2(ar[c], ai[c]);
    }
  }
  __syncthreads();

  if (PASS == 1){
    round_mid<0x000F, 0,1,2,3,   4, 0, SL,SH,false>(lds, t, f, gates);
    __syncthreads();
    round_mid<0x00F0, 4,5,6,7,   4, 0, SL,SH,false>(lds, t, f, gates);
    __syncthreads();
    round_out<0x3300, 8,9,12,13, 2, 0, SL,SH>(lds, t, f, stBase, st, gates);
  } else if (PASS == 2){
    round_mid<0x000F, 0,1,2,3,   4, 1, SL,SH,true >(lds, t, f, gates);  // sign1 then L2
    __syncthreads();
    round_mid<0x00F0, 4,5,6,7,   4, 1, SL,SH,false>(lds, t, f, gates);
    __syncthreads();
    round_out<0x3300, 8,9,12,13, 2, 1, SL,SH>(lds, t, f, stBase, st, gates);
  } else if (PASS == 3){
    round_mid<0x03C0, 6,7,8,9,   4, 1, SL,SH,false>(lds, t, f, gates);  // finish L2
    __syncthreads();
    round_mid<0x000F, 0,1,2,3,   4, 2, SL,SH,true >(lds, t, f, gates);  // sign2 then L3
    __syncthreads();
    round_out<0x3030, 4,5,12,13, 2, 2, SL,SH>(lds, t, f, stBase, st, gates);
  } else {
    round_mid<0x03C0, 6,7,8,9,   4, 2, SL,SH,false>(lds, t, f, gates);
    __syncthreads();
    float acc = round_reduce<0x003C, 2,3,4,5, SL,SH>(lds, t, f, gates, head_w);
    __syncthreads();   // all LDS reads done; reuse LDS as reduction scratch
    #pragma unroll
    for (int off = 32; off; off >>= 1) acc += __shfl_down(acc, off);
    float* red = reinterpret_cast<float*>(lds);
    if ((t & 63) == 0) red[t >> 6] = acc;
    __syncthreads();
    if (t == 0){
      float s = 0.f;
      #pragma unroll
      for (int i = 0; i < 16; ++i) s += red[i];
      partials[bg * 16 + f] = s;
    }
  }
}

__global__ void qprep(const float* __restrict__ params, float* __restrict__ gates){
  const int tid = threadIdx.x;
  if (tid < 54){
    const float x = params[tid*3+0]*0.5f, y = params[tid*3+1]*0.5f, z = params[tid*3+2]*0.5f;
    float sx,cx,sy,cy,sz,cz;
    sincosf(x,&sx,&cx); sincosf(y,&sy,&cy); sincosf(z,&sz,&cz);
    float* gp = gates + tid*8;
    gp[0] =  cz*cy*cx + sz*sy*sx;   // u00r
    gp[1] =  cz*sy*sx - sz*cy*cx;   // u00i
    gp[2] = -cz*sy*cx - sz*cy*sx;   // u01r
    gp[3] =  sz*sy*cx - cz*cy*sx;   // u01i
    gp[4] =  cz*sy*cx + sz*cy*sx;   // u10r
    gp[5] =  sz*sy*cx - cz*cy*sx;   // u10i
    gp[6] =  cz*cy*cx + sz*sy*sx;   // u11r
    gp[7] =  sz*cy*cx - cz*sy*sx;   // u11i
  }
}

__global__ void qfinal(const float* __restrict__ partials, const float* __restrict__ head_b,
                       float* __restrict__ out, int B){
  const int b = threadIdx.x + blockIdx.x * blockDim.x;
  if (b < B){
    float s = head_b[0];
    #pragma unroll
    for (int i = 0; i < 16; ++i) s += partials[b*16 + i];
    out[b] = s;
  }
}

extern "C" void kernel_launch(void* const* d_in, const int* in_sizes, int n_in,
                              void* d_out, int out_size, void* d_ws, size_t ws_size,
                              hipStream_t stream){
  const float* sr     = (const float*)d_in[0];
  const float* si     = (const float*)d_in[1];
  const float* params = (const float*)d_in[2];
  const float* head_w = (const float*)d_in[3];
  const float* head_b = (const float*)d_in[4];
  float* out = (float*)d_out;
  const int B = in_sizes[0] >> DBITS;   // 128

  float*    gates    = (float*)d_ws;                       // [0,   2048) bytes
  float*    partials = (float*)d_ws + 512;                 // [2048,10240)
  unsigned* st       = (unsigned*)((char*)d_ws + 16384);   // bf16-packed state chunk

  size_t stBytes = ws_size > 16384 ? ws_size - 16384 : 0;
  int maxChunk = (int)(stBytes / ((size_t)(1 << DBITS) * 4));
  if (maxChunk > B) maxChunk = B;
  if (maxChunk < 1) maxChunk = 1;

  qprep<<<dim3(1), dim3(64), 0, stream>>>(params, gates);

  for (int b0 = 0; b0 < B; b0 += maxChunk){
    const int c = (B - b0 < maxChunk) ? (B - b0) : maxChunk;
    dim3 grid(c * 16), blk(1024);
    qpass<1><<<grid, blk, 0, stream>>>(sr, si, st, gates, head_w, partials, b0);
    qpass<2><<<grid, blk, 0, stream>>>(sr, si, st, gates, head_w, partials, b0);
    qpass<3><<<grid, blk, 0, stream>>>(sr, si, st, gates, head_w, partials, b0);
    qpass<4><<<grid, blk, 0, stream>>>(sr, si, st, gates, head_w, partials, b0);
  }
  qfinal<<<dim3(1), dim3(128), 0, stream>>>(partials, head_b, out, B);
}